// Round 5
// baseline (231.025 us; speedup 1.0000x reference)
//
#include <hip/hip_runtime.h>
#include <hip/hip_bf16.h>
#include <cstdint>

typedef __bf16 bf16x8 __attribute__((ext_vector_type(8)));
typedef float f32x4 __attribute__((ext_vector_type(4)));

__device__ __forceinline__ float bf2f(unsigned short u) {
  union { unsigned int i; float f; } x; x.i = ((unsigned int)u) << 16; return x.f;
}
__device__ __forceinline__ unsigned short f2bf(float f) {
  __hip_bfloat16 h = __float2bfloat16(f);
  return __builtin_bit_cast(unsigned short, h);
}

__device__ __forceinline__ void gload_lds16(const void* g, void* l) {
  auto gp = reinterpret_cast<__attribute__((address_space(1))) char*>(
      reinterpret_cast<uintptr_t>(g));
  auto lp = reinterpret_cast<__attribute__((address_space(3))) char*>(
      reinterpret_cast<uintptr_t>(l));
  __builtin_amdgcn_global_load_lds(gp, lp, 16, 0, 0);
}

#define SB() __builtin_amdgcn_sched_barrier(0)
#define BAR()                         \
  do {                                \
    SB();                             \
    __builtin_amdgcn_s_barrier();     \
    SB();                             \
  } while (0)
#define LGKM0()                                          \
  do {                                                   \
    asm volatile("s_waitcnt lgkmcnt(0)" ::: "memory");   \
    SB();                                                \
  } while (0)

// T1: bijective XCD-aware block swizzle (requires total blocks % 8 == 0)
__device__ __forceinline__ void xcd_swz(int& bx, int& by, int& bz) {
  const int gx = gridDim.x, gy = gridDim.y;
  const int n = gx * gy * (int)gridDim.z;
  int lin = blockIdx.x + gx * (blockIdx.y + gy * blockIdx.z);
  lin = (lin & 7) * (n >> 3) + (lin >> 3);
  bx = lin % gx; lin /= gx;
  by = lin % gy; bz = lin / gy;
}

// ---------- fp32 -> bf16 ----------
__global__ __launch_bounds__(256) void cvt_f32_to_bf16(
    const float* __restrict__ in, unsigned short* __restrict__ out, long n4) {
  long i = (long)blockIdx.x * 256 + threadIdx.x;
  if (i >= n4) return;
  const float4 v = reinterpret_cast<const float4*>(in)[i];
  ushort4 o;
  o.x = f2bf(v.x); o.y = f2bf(v.y); o.z = f2bf(v.z); o.w = f2bf(v.w);
  reinterpret_cast<ushort4*>(out)[i] = o;
}

// ---------- all 4 weight transposes in one launch ----------
__global__ void transpose_w4(const float* __restrict__ w0,
                             const float* __restrict__ w1,
                             const float* __restrict__ w2,
                             const float* __restrict__ w3,
                             unsigned short* __restrict__ out) {
  const int z = blockIdx.z;
  const float* in = (z == 0) ? w0 : (z == 1) ? w1 : (z == 2) ? w2 : w3;
  out += (size_t)z * 1024 * 1024;
  __shared__ float tile[32][33];
  const int c0 = blockIdx.x * 32, r0 = blockIdx.y * 32;
  tile[threadIdx.y][threadIdx.x] =
      in[(size_t)(r0 + threadIdx.y) * 1024 + c0 + threadIdx.x];
  __syncthreads();
  out[(size_t)(c0 + threadIdx.y) * 1024 + r0 + threadIdx.x] =
      f2bf(tile[threadIdx.x][threadIdx.y]);
}

// ---------- bf16 transpose: out[c][r] = in[r][c] ----------
__global__ void transpose_bf16(const unsigned short* __restrict__ in,
                               unsigned short* __restrict__ out,
                               int ldIn, int ldOut, long sIn, long sOut) {
  in  += (long)blockIdx.z * sIn;
  out += (long)blockIdx.z * sOut;
  __shared__ unsigned short tile[32][33];
  const int c0 = blockIdx.x * 32, r0 = blockIdx.y * 32;
  tile[threadIdx.y][threadIdx.x] =
      in[(size_t)(r0 + threadIdx.y) * ldIn + c0 + threadIdx.x];
  __syncthreads();
  out[(size_t)(c0 + threadIdx.y) * ldOut + r0 + threadIdx.x] =
      tile[threadIdx.x][threadIdx.y];
}

__global__ void concat_bias3(const float* a, const float* b, const float* c,
                             float* o) {
  int i = blockIdx.x * 256 + threadIdx.x;
  if (i >= 3072) return;
  o[i] = (i < 1024) ? a[i] : (i < 2048 ? b[i - 1024] : c[i - 2048]);
}

// ===== staging / frag macros (XOR swizzle: both-sides involution) =====
#define STAGE128(gbase, ld, ldsbase, rowbase)                                 \
  {                                                                           \
    _Pragma("unroll") for (int l_ = 0; l_ < 2; ++l_) {                        \
      const int seg_ = (w << 1) + l_;                                         \
      const int r0_ = (rowbase) + (seg_ << 3);                                \
      const int gr_ = r0_ + (lane >> 3);                                      \
      const int sc_ = ((lane & 7) ^ (lane >> 3)) << 3;                        \
      gload_lds16((gbase) + (size_t)gr_ * (ld) + sc_, (ldsbase) + r0_ * 64);  \
    }                                                                         \
  }
#define STAGE_A(gbase, ld, ldsbase, h)                                        \
  {                                                                           \
    _Pragma("unroll") for (int l_ = 0; l_ < 2; ++l_) {                        \
      const int seg_ = (w << 1) + l_;                                         \
      const int r0_ = ((seg_ >> 3) << 7) + ((h) << 6) + ((seg_ & 7) << 3);    \
      const int gr_ = r0_ + (lane >> 3);                                      \
      const int sc_ = ((lane & 7) ^ (lane >> 3)) << 3;                        \
      gload_lds16((gbase) + (size_t)gr_ * (ld) + sc_, (ldsbase) + r0_ * 64);  \
    }                                                                         \
  }
#define STAGE_B(gbase, ld, ldsbase, h)                                        \
  {                                                                           \
    _Pragma("unroll") for (int l_ = 0; l_ < 2; ++l_) {                        \
      const int seg_ = (w << 1) + l_;                                         \
      const int r0_ = ((seg_ >> 2) << 6) + ((h) << 5) + ((seg_ & 3) << 3);    \
      const int gr_ = r0_ + (lane >> 3);                                      \
      const int sc_ = ((lane & 7) ^ (lane >> 3)) << 3;                        \
      gload_lds16((gbase) + (size_t)gr_ * (ld) + sc_, (ldsbase) + r0_ * 64);  \
    }                                                                         \
  }

#define LDA_FRAG(dst, tile, rbase)                                            \
  _Pragma("unroll") for (int m_ = 0; m_ < 4; ++m_)                            \
  _Pragma("unroll") for (int kk_ = 0; kk_ < 2; ++kk_) {                       \
    const int row_ = (rbase) + (m_ << 4) + (lane & 15);                       \
    const int ch_ = ((kk_ << 2) + (lane >> 4)) ^ (lane & 7);                  \
    dst[m_][kk_] =                                                            \
        *reinterpret_cast<const bf16x8*>((tile) + row_ * 64 + (ch_ << 3));    \
  }
#define LDB_FRAG(dst, tile, rbase)                                            \
  _Pragma("unroll") for (int n_ = 0; n_ < 2; ++n_)                            \
  _Pragma("unroll") for (int kk_ = 0; kk_ < 2; ++kk_) {                       \
    const int row_ = (rbase) + (n_ << 4) + (lane & 15);                       \
    const int ch_ = ((kk_ << 2) + (lane >> 4)) ^ (lane & 7);                  \
    dst[n_][kk_] =                                                            \
        *reinterpret_cast<const bf16x8*>((tile) + row_ * 64 + (ch_ << 3));    \
  }

// SWAPPED operand order: mfma(b, a, acc) -> per lane, D holds 4 consecutive
// N-cols (reg i) at a fixed M-row (lane&15) -> vec4 C-stores.
#define MFMA_QUAD(a_, b_, af_, bf_)                                           \
  __builtin_amdgcn_s_setprio(1);                                              \
  _Pragma("unroll") for (int m_ = 0; m_ < 4; ++m_)                            \
  _Pragma("unroll") for (int n_ = 0; n_ < 2; ++n_)                            \
  _Pragma("unroll") for (int kk_ = 0; kk_ < 2; ++kk_)                         \
      acc[(a_) * 4 + m_][(b_) * 2 + n_] =                                     \
          __builtin_amdgcn_mfma_f32_16x16x32_bf16(                            \
              bf_[n_][kk_], af_[m_][kk_], acc[(a_) * 4 + m_][(b_) * 2 + n_],  \
              0, 0, 0);                                                       \
  __builtin_amdgcn_s_setprio(0);

#define MFMA_QUAD128(b_, af_, bf_)                                            \
  __builtin_amdgcn_s_setprio(1);                                              \
  _Pragma("unroll") for (int m_ = 0; m_ < 4; ++m_)                            \
  _Pragma("unroll") for (int n_ = 0; n_ < 2; ++n_)                            \
  _Pragma("unroll") for (int kk_ = 0; kk_ < 2; ++kk_)                         \
      acc[m_][(b_) * 2 + n_] = __builtin_amdgcn_mfma_f32_16x16x32_bf16(       \
          bf_[n_][kk_], af_[m_][kk_], acc[m_][(b_) * 2 + n_], 0, 0, 0);       \
  __builtin_amdgcn_s_setprio(0);

// =====================================================================
// gemm256p: PERSISTENT 256x256-tile GEMM, K=1024 (NT=16), 256 blocks.
// Flat kg iteration across this block's tiles {g, g+256, ...}: the staging
// pipeline rolls seamlessly across output-tile boundaries (no drain; the
// counted vmcnt(6) holds through the switch). Epilogue overlaps the next
// tile's in-flight prefetch. tile jj: bz=jj/txy, m0=((jj%txy)/tx)*256,
// n0=(jj%tx)*256.
// =====================================================================
template <typename OutT, bool HAS_BIAS>
__global__ __launch_bounds__(512, 2) void gemm256p(
    const unsigned short* __restrict__ A,
    const unsigned short* __restrict__ Bt,
    OutT* __restrict__ C,
    const float* __restrict__ bias,
    int lda, int ldb, int ldc, float scale,
    int tilesTotal, int tx, int txy,
    long sA, long sB, long sC) {
  const int gphys = blockIdx.x;
  const int g = ((gphys & 7) << 5) + (gphys >> 3);  // XCD-chunked, 256 blocks
  __shared__ __attribute__((aligned(16))) unsigned short lds[2 * 32768];
  const int t = threadIdx.x;
  const int lane = t & 63;
  const int w = t >> 6;
  const int wm = w >> 2, wn = w & 3;

  const int ntb = (tilesTotal - g + 255) >> 8;  // tiles for this block
  const int myTotK = ntb << 4;                  // NT=16 per tile

  // current tile
  int jj = g;
  int m0c = ((jj % txy) / tx) << 8;
  int n0c = (jj % tx) << 8;
  const unsigned short* gAc = A + (long)(jj / txy) * sA + (size_t)m0c * lda;
  const unsigned short* gBc = Bt + (long)(jj / txy) * sB + (size_t)n0c * ldb;
  OutT* Cc = C + (long)(jj / txy) * sC;
  // next tile (valid only if ntb > 1)
  int jn = jj + 256;
  const unsigned short* gAn = gAc;
  const unsigned short* gBn = gBc;
  if (jn < tilesTotal) {
    gAn = A + (long)(jn / txy) * sA + (size_t)(((jn % txy) / tx) << 8) * lda;
    gBn = Bt + (long)(jn / txy) * sB + (size_t)((jn % tx) << 8) * ldb;
  }

  f32x4 acc[8][4];
  const f32x4 vz = {0.f, 0.f, 0.f, 0.f};
#pragma unroll
  for (int i = 0; i < 8; ++i)
#pragma unroll
    for (int j = 0; j < 4; ++j) acc[i][j] = vz;

  // prologue: tile kg=0 fully + kg=1 {Ah0,Bh0,Bh1}
  {
    unsigned short* a0 = lds;
    unsigned short* b0t = lds + 16384;
    STAGE_A(gAc, lda, a0, 0);
    STAGE_B(gBc, ldb, b0t, 0);
    STAGE_B(gBc, ldb, b0t, 1);
    STAGE_A(gAc, lda, a0, 1);
    if (myTotK > 1) {
      unsigned short* a1 = lds + 32768;
      unsigned short* b1t = lds + 32768 + 16384;
      STAGE_A(gAc + 64, lda, a1, 0);
      STAGE_B(gBc + 64, ldb, b1t, 0);
      STAGE_B(gBc + 64, ldb, b1t, 1);
      asm volatile("s_waitcnt vmcnt(6)" ::: "memory");
    } else {
      asm volatile("s_waitcnt vmcnt(0)" ::: "memory");
    }
  }
  BAR();

  for (int kg = 0; kg < myTotK; ++kg) {
    const int kt = kg & 15;
    unsigned short* at = lds + ((kg & 1) << 15);
    unsigned short* bt = at + 16384;
    unsigned short* atN = lds + (((kg + 1) & 1) << 15);
    // staging sources (cross tile boundary at kt>=14)
    const unsigned short* pA1 = (kt < 15) ? gAc + (size_t)(kt + 1) * 64 : gAn;
    const unsigned short* pA2 =
        (kt < 14) ? gAc + (size_t)(kt + 2) * 64 : gAn + (size_t)(kt - 14) * 64;
    const unsigned short* pB2 =
        (kt < 14) ? gBc + (size_t)(kt + 2) * 64 : gBn + (size_t)(kt - 14) * 64;
    const bool s1 = kg + 1 < myTotK, s2 = kg + 2 < myTotK;

    bf16x8 af[4][2], b0[2][2], b1[2][2];

    LDA_FRAG(af, at, (wm << 7));
    LDB_FRAG(b0, bt, (wn << 6));
    if (s1) STAGE_A(pA1, lda, atN, 1);
    BAR();
    LGKM0();
    MFMA_QUAD(0, 0, af, b0);
    BAR();

    LDB_FRAG(b1, bt, (wn << 6) + 32);
    if (s2) STAGE_A(pA2, lda, at, 0);
    BAR();
    LGKM0();
    MFMA_QUAD(0, 1, af, b1);
    BAR();

    LDA_FRAG(af, at, (wm << 7) + 64);
    if (s2) STAGE_B(pB2, ldb, bt, 0);
    BAR();
    LGKM0();
    MFMA_QUAD(1, 0, af, b0);
    BAR();

    if (s2) STAGE_B(pB2, ldb, bt, 1);
    if (kg < myTotK - 3) {
      asm volatile("s_waitcnt vmcnt(6)" ::: "memory");
    } else {
      asm volatile("s_waitcnt vmcnt(0)" ::: "memory");
    }
    BAR();
    MFMA_QUAD(1, 1, af, b1);
    BAR();

    if (kt == 15) {
      // epilogue: swapped layout -> vec4 stores
      const int mrow0 = m0c + (wm << 7) + (lane & 15);
      const int ncol0 = n0c + (wn << 6) + ((lane >> 4) << 2);
#pragma unroll
      for (int mf = 0; mf < 8; ++mf) {
        const int row = mrow0 + (mf << 4);
#pragma unroll
        for (int nf = 0; nf < 4; ++nf) {
          const int col = ncol0 + (nf << 4);
          float4 bb = {0.f, 0.f, 0.f, 0.f};
          if (HAS_BIAS) bb = *reinterpret_cast<const float4*>(bias + col);
          const f32x4 a = acc[mf][nf];
          if constexpr (sizeof(OutT) == 2) {
            ushort4 o;
            o.x = f2bf(a[0] * scale + bb.x);
            o.y = f2bf(a[1] * scale + bb.y);
            o.z = f2bf(a[2] * scale + bb.z);
            o.w = f2bf(a[3] * scale + bb.w);
            *reinterpret_cast<ushort4*>(&Cc[(size_t)row * ldc + col]) = o;
          } else {
            float4 o;
            o.x = a[0] * scale + bb.x;
            o.y = a[1] * scale + bb.y;
            o.z = a[2] * scale + bb.z;
            o.w = a[3] * scale + bb.w;
            *reinterpret_cast<float4*>(&Cc[(size_t)row * ldc + col]) = o;
          }
        }
      }
      if (kg + 1 < myTotK) {
        // advance to next tile
        jj = jn;
        m0c = ((jj % txy) / tx) << 8;
        n0c = (jj % tx) << 8;
        gAc = gAn;
        gBc = gBn;
        Cc = C + (long)(jj / txy) * sC;
        jn = jj + 256;
        if (jn < tilesTotal) {
          gAn = A + (long)(jn / txy) * sA + (size_t)(((jn % txy) / tx) << 8) * lda;
          gBn = Bt + (long)(jn / txy) * sB + (size_t)((jn % tx) << 8) * ldb;
        }
#pragma unroll
        for (int i = 0; i < 8; ++i)
#pragma unroll
          for (int j = 0; j < 4; ++j) acc[i][j] = vz;
      }
    }
  }
}

// =====================================================================
// gemm128t: BM=256 x BN=128, 8 waves (4M x 2N), per-wave 64x64, acc[4][4].
// Triple-buffered LDS, distance-2 tile prefetch (round-3 structure).
// Swapped-operand epilogue (vec4 stores).
// =====================================================================
template <typename OutT, bool HAS_BIAS>
__global__ __launch_bounds__(512, 2) void gemm128t(
    const unsigned short* __restrict__ A,
    const unsigned short* __restrict__ Bt,
    OutT* __restrict__ C,
    const float* __restrict__ bias,
    int K, int lda, int ldb, int ldc, float scale,
    long sA, long sB, long sC) {
  int bx, by, bz;
  xcd_swz(bx, by, bz);
  A  += (long)bz * sA;
  Bt += (long)bz * sB;
  C  += (long)bz * sC;
  const int n0 = bx << 7;
  const int m0 = by << 8;
  __shared__ __attribute__((aligned(16))) unsigned short lds[3 * 24576];
  const int t = threadIdx.x;
  const int lane = t & 63;
  const int w = t >> 6;
  const int wm = w >> 1, wn = w & 1;
  const unsigned short* gA = A + (size_t)m0 * lda;
  const unsigned short* gB = Bt + (size_t)n0 * ldb;
  const int NT = K >> 6;

  f32x4 acc[4][4];
  const f32x4 vz = {0.f, 0.f, 0.f, 0.f};
#pragma unroll
  for (int i = 0; i < 4; ++i)
#pragma unroll
    for (int j = 0; j < 4; ++j) acc[i][j] = vz;

  {
    STAGE128(gA, lda, lds, 0);
    STAGE128(gA, lda, lds, 128);
    STAGE128(gB, ldb, lds + 16384, 0);
    STAGE128(gA + 64, lda, lds + 24576, 0);
    STAGE128(gA + 64, lda, lds + 24576, 128);
    STAGE128(gB + 64, ldb, lds + 24576 + 16384, 0);
    asm volatile("s_waitcnt vmcnt(6)" ::: "memory");
  }
  BAR();

  int idx = 0;
  for (int kt = 0; kt < NT; ++kt) {
    unsigned short* at = lds + idx * 24576;
    unsigned short* btile = at + 16384;
    int idx2 = idx + 2; if (idx2 >= 3) idx2 -= 3;
    unsigned short* st = lds + idx2 * 24576;
    const unsigned short* gA2 = gA + (size_t)(kt + 2) * 64;
    const unsigned short* gB2 = gB + (size_t)(kt + 2) * 64;
    const bool st2 = kt + 2 < NT;

    bf16x8 af[4][2], b0[2][2], b1[2][2];

    LDA_FRAG(af, at, (wm << 6));
    LDB_FRAG(b0, btile, (wn << 6));
    if (st2) {
      STAGE128(gA2, lda, st, 0);
      STAGE128(gA2, lda, st, 128);
    }
    BAR();
    LGKM0();
    MFMA_QUAD128(0, af, b0);
    BAR();

    LDB_FRAG(b1, btile, (wn << 6) + 32);
    if (st2) STAGE128(gB2, ldb, st + 16384, 0);
    if (kt < NT - 2) {
      asm volatile("s_waitcnt vmcnt(6)" ::: "memory");
    } else {
      asm volatile("s_waitcnt vmcnt(0)" ::: "memory");
    }
    BAR();
    LGKM0();
    MFMA_QUAD128(1, af, b1);
    BAR();

    idx = (idx + 1 == 3) ? 0 : idx + 1;
  }

  const int mrow0 = m0 + (wm << 6) + (lane & 15);
  const int ncol0 = n0 + (wn << 6) + ((lane >> 4) << 2);
#pragma unroll
  for (int mf = 0; mf < 4; ++mf) {
    const int row = mrow0 + (mf << 4);
#pragma unroll
    for (int nf = 0; nf < 4; ++nf) {
      const int col = ncol0 + (nf << 4);
      float4 bb = {0.f, 0.f, 0.f, 0.f};
      if (HAS_BIAS) bb = *reinterpret_cast<const float4*>(bias + col);
      const f32x4 a = acc[mf][nf];
      if constexpr (sizeof(OutT) == 2) {
        ushort4 o;
        o.x = f2bf(a[0] * scale + bb.x);
        o.y = f2bf(a[1] * scale + bb.y);
        o.z = f2bf(a[2] * scale + bb.z);
        o.w = f2bf(a[3] * scale + bb.w);
        *reinterpret_cast<ushort4*>(&C[(size_t)row * ldc + col]) = o;
      } else {
        float4 o;
        o.x = a[0] * scale + bb.x;
        o.y = a[1] * scale + bb.y;
        o.z = a[2] * scale + bb.z;
        o.w = a[3] * scale + bb.w;
        *reinterpret_cast<float4*>(&C[(size_t)row * ldc + col]) = o;
      }
    }
  }
}

// ---------- row softmax, in place, bf16, one block per row ----------
__global__ __launch_bounds__(256) void softmax_inplace(
    unsigned short* __restrict__ P, int S) {
  const size_t row = blockIdx.x;
  unsigned short* p = P + row * (size_t)S;
  const int t = threadIdx.x;
  const int lane = t & 63, w = t >> 6;
  const uint4 raw = reinterpret_cast<const uint4*>(p)[t];
  unsigned int u[4] = {raw.x, raw.y, raw.z, raw.w};
  float v[8];
#pragma unroll
  for (int j = 0; j < 4; ++j) {
    v[2 * j]     = bf2f((unsigned short)(u[j] & 0xffffu));
    v[2 * j + 1] = bf2f((unsigned short)(u[j] >> 16));
  }
  float mx = v[0];
#pragma unroll
  for (int j = 1; j < 8; ++j) mx = fmaxf(mx, v[j]);
#pragma unroll
  for (int off = 32; off >= 1; off >>= 1) mx = fmaxf(mx, __shfl_xor(mx, off, 64));
  __shared__ float red[4];
  if (lane == 0) red[w] = mx;
  __syncthreads();
  mx = fmaxf(fmaxf(red[0], red[1]), fmaxf(red[2], red[3]));
  float e[8];
  float s = 0.f;
#pragma unroll
  for (int j = 0; j < 8; ++j) { e[j] = __expf(v[j] - mx); s += e[j]; }
#pragma unroll
  for (int off = 32; off >= 1; off >>= 1) s += __shfl_xor(s, off, 64);
  __syncthreads();
  if (lane == 0) red[w] = s;
  __syncthreads();
  s = red[0] + red[1] + red[2] + red[3];
  const float inv = 1.f / s;
  unsigned int o[4];
#pragma unroll
  for (int j = 0; j < 4; ++j)
    o[j] = (unsigned int)f2bf(e[2 * j] * inv) |
           ((unsigned int)f2bf(e[2 * j + 1] * inv) << 16);
  uint4 ov; ov.x = o[0]; ov.y = o[1]; ov.z = o[2]; ov.w = o[3];
  reinterpret_cast<uint4*>(p)[t] = ov;
}

// ---------- launch ----------
extern "C" void kernel_launch(void* const* d_in, const int* in_sizes, int n_in,
                              void* d_out, int out_size, void* d_ws, size_t ws_size,
                              hipStream_t stream) {
  (void)in_sizes; (void)n_in; (void)out_size; (void)ws_size;
  const float* x  = (const float*)d_in[0];
  const float* Wq = (const float*)d_in[1];
  const float* bq = (const float*)d_in[2];
  const float* Wk = (const float*)d_in[3];
  const float* bk = (const float*)d_in[4];
  const float* Wv = (const float*)d_in[5];
  const float* bv = (const float*)d_in[6];
  const float* Wo = (const float*)d_in[7];
  const float* bo = (const float*)d_in[8];
  float* out = (float*)d_out;

  constexpr int B = 4, S = 2048, D = 1024;
  constexpr long BS = (long)B * S;  // 8192
  constexpr size_t MB = 1ull << 20;
  char* ws = (char*)d_ws;
  unsigned short* xb   = (unsigned short*)(ws + 0);         // 16MB (dead after QKV)
  unsigned short* Wall = (unsigned short*)(ws + 16 * MB);   // 8MB [4][1024][1024]
  float*          bqkv = (float*)(ws + 24 * MB);            // 12KB
  unsigned short* QKVc = (unsigned short*)(ws + 25 * MB);   // 48MB [8192][3072]
  unsigned short* Sc   = (unsigned short*)(ws + 73 * MB);   // 32MB
  unsigned short* Vt   = (unsigned short*)(ws + 105 * MB);  // 16MB [4][1024][2048]
  unsigned short* AO   = (unsigned short*)(ws + 0);         // 16MB (over xb)

  const float scale = 0.03125f;  // 1/sqrt(1024)

  cvt_f32_to_bf16<<<(BS * D / 4 + 255) / 256, 256, 0, stream>>>(x, xb, BS * D / 4);
  transpose_w4<<<dim3(32, 32, 4), dim3(32, 32), 0, stream>>>(Wq, Wk, Wv, Wo, Wall);
  concat_bias3<<<12, 256, 0, stream>>>(bq, bk, bv, bqkv);

  // fused QKV projection, persistent: 384 tiles / 256 blocks
  gemm256p<unsigned short, true><<<256, 512, 0, stream>>>(
      xb, Wall, QKVc, bqkv, D, D, 3072, 1.f, 384, 12, 384, 0, 0, 0);

  // V^T per batch: Vt[b][d][s] = QKVc[b*S+s][2048+d]
  transpose_bf16<<<dim3(32, 64, 4), dim3(32, 32), 0, stream>>>(
      QKVc + 2048, Vt, 3072, S, (long)S * 3072, (long)D * S);

  // scores[b] = scale * Q[b] @ K[b]^T (persistent kernel, 1 tile/block)
  gemm256p<unsigned short, false><<<256, 512, 0, stream>>>(
      QKVc + 0, QKVc + 1024, Sc, nullptr, 3072, 3072, S, scale,
      256, 8, 64, (long)S * 3072, (long)S * 3072, (long)S * S);

  softmax_inplace<<<B * S, 256, 0, stream>>>(Sc, S);

  // attn_out[b] = P[b] @ V[b] via Vt: M=2048, N=1024, K=2048
  gemm128t<unsigned short, false><<<dim3(8, 8, 4), 512, 0, stream>>>(
      Sc, Vt, AO, nullptr, S, S, S, D, 1.f,
      (long)S * S, (long)D * S, (long)S * D);

  // out = AO @ Wot^T + bo (fp32), M=8192, N=1024
  gemm128t<float, true><<<dim3(8, 32, 1), 512, 0, stream>>>(
      AO, Wall + 3 * 1024 * 1024, out, bo, D, D, D, D, 1.f, 0, 0, 0);
}

// Round 6
// 207.605 us; speedup vs baseline: 1.1128x; 1.1128x over previous
//
#include <hip/hip_runtime.h>
#include <hip/hip_bf16.h>
#include <cstdint>

typedef __bf16 bf16x8 __attribute__((ext_vector_type(8)));
typedef float f32x4 __attribute__((ext_vector_type(4)));

__device__ __forceinline__ float bf2f(unsigned short u) {
  union { unsigned int i; float f; } x; x.i = ((unsigned int)u) << 16; return x.f;
}
__device__ __forceinline__ unsigned short f2bf(float f) {
  __hip_bfloat16 h = __float2bfloat16(f);
  return __builtin_bit_cast(unsigned short, h);
}

__device__ __forceinline__ void gload_lds16(const void* g, void* l) {
  auto gp = reinterpret_cast<__attribute__((address_space(1))) char*>(
      reinterpret_cast<uintptr_t>(g));
  auto lp = reinterpret_cast<__attribute__((address_space(3))) char*>(
      reinterpret_cast<uintptr_t>(l));
  __builtin_amdgcn_global_load_lds(gp, lp, 16, 0, 0);
}

// T1: bijective XCD-aware block swizzle (requires total blocks % 8 == 0)
__device__ __forceinline__ void xcd_swz(int& bx, int& by, int& bz) {
  const int gx = gridDim.x, gy = gridDim.y;
  const int n = gx * gy * (int)gridDim.z;
  int lin = blockIdx.x + gx * (blockIdx.y + gy * blockIdx.z);
  lin = (lin & 7) * (n >> 3) + (lin >> 3);
  bx = lin % gx; lin /= gx;
  by = lin % gy; bz = lin / gy;
}

// ---------- fp32 -> bf16 ----------
__global__ __launch_bounds__(256) void cvt_f32_to_bf16(
    const float* __restrict__ in, unsigned short* __restrict__ out, long n4) {
  long i = (long)blockIdx.x * 256 + threadIdx.x;
  if (i >= n4) return;
  const float4 v = reinterpret_cast<const float4*>(in)[i];
  ushort4 o;
  o.x = f2bf(v.x); o.y = f2bf(v.y); o.z = f2bf(v.z); o.w = f2bf(v.w);
  reinterpret_cast<ushort4*>(out)[i] = o;
}

// ---------- all 4 weight transposes in one launch ----------
__global__ void transpose_w4(const float* __restrict__ w0,
                             const float* __restrict__ w1,
                             const float* __restrict__ w2,
                             const float* __restrict__ w3,
                             unsigned short* __restrict__ out) {
  const int z = blockIdx.z;
  const float* in = (z == 0) ? w0 : (z == 1) ? w1 : (z == 2) ? w2 : w3;
  out += (size_t)z * 1024 * 1024;
  __shared__ float tile[32][33];
  const int c0 = blockIdx.x * 32, r0 = blockIdx.y * 32;
  tile[threadIdx.y][threadIdx.x] =
      in[(size_t)(r0 + threadIdx.y) * 1024 + c0 + threadIdx.x];
  __syncthreads();
  out[(size_t)(c0 + threadIdx.y) * 1024 + r0 + threadIdx.x] =
      f2bf(tile[threadIdx.x][threadIdx.y]);
}

__global__ void concat_bias3(const float* a, const float* b, const float* c,
                             float* o) {
  int i = blockIdx.x * 256 + threadIdx.x;
  if (i >= 3072) return;
  o[i] = (i < 1024) ? a[i] : (i < 2048 ? b[i - 1024] : c[i - 2048]);
}

// =====================================================================
// gemm_hi: m97-structure 128x128 tile GEMM, HIGH OCCUPANCY (target 4
// blocks/CU): 256 threads = 4 waves (2M x 2N), per-wave 64x64, BK=64,
// SINGLE-buffered 32KB LDS, XOR bank-swizzle (T2, both-sides), plain
// __syncthreads (compiler emits the waitcnts), no asm scheduling.
// Inter-block wave overlap on the CU provides the pipelining (m114/m97).
// C[M][N] = scale*(A[M][K] @ Bt[N][K]^T) + bias.
// VSPLIT (QKV): cols n0>=2048 are V -> written transposed to vt[b][d][s];
// uses non-swapped MFMA so acc regs run along M(=s) for vec4 Vt stores.
// Otherwise swapped MFMA (regs along N) for vec4 C stores.
// =====================================================================
template <typename OutT, bool HAS_BIAS, bool VSPLIT>
__global__ __launch_bounds__(256, 4) void gemm_hi(
    const unsigned short* __restrict__ A,
    const unsigned short* __restrict__ Bt,
    OutT* __restrict__ C,
    const float* __restrict__ bias,
    unsigned short* __restrict__ vt,
    int K, int lda, int ldb, int ldc, float scale,
    long sA, long sB, long sC) {
  int bx, by, bz;
  xcd_swz(bx, by, bz);
  A  += (long)bz * sA;
  Bt += (long)bz * sB;
  C  += (long)bz * sC;
  const int n0 = bx << 7;
  const int m0 = by << 7;
  __shared__ __attribute__((aligned(16))) unsigned short As[128 * 64];
  __shared__ __attribute__((aligned(16))) unsigned short Bs[128 * 64];
  const int t = threadIdx.x;
  const int lane = t & 63;
  const int w = t >> 6;           // 4 waves
  const int wm = w >> 1, wn = w & 1;
  const unsigned short* gA = A + (size_t)m0 * lda;
  const unsigned short* gB = Bt + (size_t)n0 * ldb;
  const int NT = K >> 6;

  // staging lane geometry (inverse-swizzled global source, linear LDS dest)
  const int srow = lane >> 3;                     // 0..7 within 8-row group
  const int scol = ((lane & 7) ^ srow) << 3;      // XOR-swizzled col chunk

  f32x4 acc[4][4];
  const f32x4 vz = {0.f, 0.f, 0.f, 0.f};
#pragma unroll
  for (int i = 0; i < 4; ++i)
#pragma unroll
    for (int j = 0; j < 4; ++j) acc[i][j] = vz;

  for (int kt = 0; kt < NT; ++kt) {
    const unsigned short* pA = gA + (size_t)kt * 64;
    const unsigned short* pB = gB + (size_t)kt * 64;
    // stage A tile (128x64) + B tile (128x64): 8 x gload_lds16 per thread
#pragma unroll
    for (int i = 0; i < 4; ++i) {
      const int r0 = (w << 3) + (i << 5);  // wave w stages rows w*8 in each 32-row band
      gload_lds16(pA + (size_t)(r0 + srow) * lda + scol, As + r0 * 64);
      gload_lds16(pB + (size_t)(r0 + srow) * ldb + scol, Bs + r0 * 64);
    }
    __syncthreads();  // drains vmcnt -> tiles resident

#pragma unroll
    for (int kk = 0; kk < 2; ++kk) {
      bf16x8 af[4], bg[4];
      const int ch = ((kk << 2) + (lane >> 4)) ^ (lane & 7);
#pragma unroll
      for (int m = 0; m < 4; ++m) {
        const int row = (wm << 6) + (m << 4) + (lane & 15);
        af[m] = *reinterpret_cast<const bf16x8*>(As + row * 64 + (ch << 3));
      }
#pragma unroll
      for (int n = 0; n < 4; ++n) {
        const int row = (wn << 6) + (n << 4) + (lane & 15);
        bg[n] = *reinterpret_cast<const bf16x8*>(Bs + row * 64 + (ch << 3));
      }
#pragma unroll
      for (int m = 0; m < 4; ++m)
#pragma unroll
        for (int n = 0; n < 4; ++n) {
          if constexpr (VSPLIT) {
            // non-swapped: acc regs run along M (= s) for Vt vec4 stores
            acc[m][n] = __builtin_amdgcn_mfma_f32_16x16x32_bf16(
                af[m], bg[n], acc[m][n], 0, 0, 0);
          } else {
            // swapped: acc regs run along N for vec4 C stores
            acc[m][n] = __builtin_amdgcn_mfma_f32_16x16x32_bf16(
                bg[n], af[m], acc[m][n], 0, 0, 0);
          }
        }
    }
    __syncthreads();  // protect LDS from next tile's staging
  }

  if constexpr (VSPLIT) {
    // C/D (non-swapped): col = lane&15 (N), row = (lane>>4)*4 + i (M)
    const int crow0 = m0 + (wm << 6) + ((lane >> 4) << 2);
    const int ccol0 = n0 + (wn << 6) + (lane & 15);
    if (n0 >= 2048) {
      const int b = m0 >> 11;  // 128-row tiles never cross a 2048-row batch
#pragma unroll
      for (int mf = 0; mf < 4; ++mf) {
#pragma unroll
        for (int nf = 0; nf < 4; ++nf) {
          const int col = ccol0 + (nf << 4);
          const float bb = HAS_BIAS ? bias[col] : 0.f;
          const int d = col - 2048;
          const int s = (crow0 & 2047) + (mf << 4);
          ushort4 o;
          o.x = f2bf(acc[mf][nf][0] * scale + bb);
          o.y = f2bf(acc[mf][nf][1] * scale + bb);
          o.z = f2bf(acc[mf][nf][2] * scale + bb);
          o.w = f2bf(acc[mf][nf][3] * scale + bb);
          *reinterpret_cast<ushort4*>(
              vt + (((size_t)b << 10) + d) * 2048 + s) = o;
        }
      }
    } else {
#pragma unroll
      for (int mf = 0; mf < 4; ++mf) {
#pragma unroll
        for (int nf = 0; nf < 4; ++nf) {
          const int col = ccol0 + (nf << 4);
          const float bb = HAS_BIAS ? bias[col] : 0.f;
#pragma unroll
          for (int i = 0; i < 4; ++i) {
            const int row = crow0 + (mf << 4) + i;
            C[(size_t)row * ldc + col] =
                (OutT)f2bf(acc[mf][nf][i] * scale + bb);
          }
        }
      }
    }
  } else {
    // C/D (swapped): row = lane&15 (M), col regs = 4 consecutive N
    const int mrow0 = m0 + (wm << 6) + (lane & 15);
    const int ncol0 = n0 + (wn << 6) + ((lane >> 4) << 2);
#pragma unroll
    for (int mf = 0; mf < 4; ++mf) {
      const int row = mrow0 + (mf << 4);
#pragma unroll
      for (int nf = 0; nf < 4; ++nf) {
        const int col = ncol0 + (nf << 4);
        float4 bb = {0.f, 0.f, 0.f, 0.f};
        if (HAS_BIAS) bb = *reinterpret_cast<const float4*>(bias + col);
        const f32x4 a = acc[mf][nf];
        if constexpr (sizeof(OutT) == 2) {
          ushort4 o;
          o.x = f2bf(a[0] * scale + bb.x);
          o.y = f2bf(a[1] * scale + bb.y);
          o.z = f2bf(a[2] * scale + bb.z);
          o.w = f2bf(a[3] * scale + bb.w);
          *reinterpret_cast<ushort4*>(&C[(size_t)row * ldc + col]) = o;
        } else {
          float4 o;
          o.x = a[0] * scale + bb.x;
          o.y = a[1] * scale + bb.y;
          o.z = a[2] * scale + bb.z;
          o.w = a[3] * scale + bb.w;
          *reinterpret_cast<float4*>(&C[(size_t)row * ldc + col]) = o;
        }
      }
    }
  }
}

// ---------- row softmax, in place, bf16, one block per row ----------
__global__ __launch_bounds__(256) void softmax_inplace(
    unsigned short* __restrict__ P, int S) {
  const size_t row = blockIdx.x;
  unsigned short* p = P + row * (size_t)S;
  const int t = threadIdx.x;
  const int lane = t & 63, w = t >> 6;
  const uint4 raw = reinterpret_cast<const uint4*>(p)[t];
  unsigned int u[4] = {raw.x, raw.y, raw.z, raw.w};
  float v[8];
#pragma unroll
  for (int j = 0; j < 4; ++j) {
    v[2 * j]     = bf2f((unsigned short)(u[j] & 0xffffu));
    v[2 * j + 1] = bf2f((unsigned short)(u[j] >> 16));
  }
  float mx = v[0];
#pragma unroll
  for (int j = 1; j < 8; ++j) mx = fmaxf(mx, v[j]);
#pragma unroll
  for (int off = 32; off >= 1; off >>= 1) mx = fmaxf(mx, __shfl_xor(mx, off, 64));
  __shared__ float red[4];
  if (lane == 0) red[w] = mx;
  __syncthreads();
  mx = fmaxf(fmaxf(red[0], red[1]), fmaxf(red[2], red[3]));
  float e[8];
  float s = 0.f;
#pragma unroll
  for (int j = 0; j < 8; ++j) { e[j] = __expf(v[j] - mx); s += e[j]; }
#pragma unroll
  for (int off = 32; off >= 1; off >>= 1) s += __shfl_xor(s, off, 64);
  __syncthreads();
  if (lane == 0) red[w] = s;
  __syncthreads();
  s = red[0] + red[1] + red[2] + red[3];
  const float inv = 1.f / s;
  unsigned int o[4];
#pragma unroll
  for (int j = 0; j < 4; ++j)
    o[j] = (unsigned int)f2bf(e[2 * j] * inv) |
           ((unsigned int)f2bf(e[2 * j + 1] * inv) << 16);
  uint4 ov; ov.x = o[0]; ov.y = o[1]; ov.z = o[2]; ov.w = o[3];
  reinterpret_cast<uint4*>(p)[t] = ov;
}

// ---------- launch ----------
extern "C" void kernel_launch(void* const* d_in, const int* in_sizes, int n_in,
                              void* d_out, int out_size, void* d_ws, size_t ws_size,
                              hipStream_t stream) {
  (void)in_sizes; (void)n_in; (void)out_size; (void)ws_size;
  const float* x  = (const float*)d_in[0];
  const float* Wq = (const float*)d_in[1];
  const float* bq = (const float*)d_in[2];
  const float* Wk = (const float*)d_in[3];
  const float* bk = (const float*)d_in[4];
  const float* Wv = (const float*)d_in[5];
  const float* bv = (const float*)d_in[6];
  const float* Wo = (const float*)d_in[7];
  const float* bo = (const float*)d_in[8];
  float* out = (float*)d_out;

  constexpr int B = 4, S = 2048, D = 1024;
  constexpr long BS = (long)B * S;  // 8192
  constexpr size_t MB = 1ull << 20;
  char* ws = (char*)d_ws;
  unsigned short* xb   = (unsigned short*)(ws + 0);        // 16MB (dead after QKV)
  unsigned short* Wall = (unsigned short*)(ws + 16 * MB);  // 8MB [4][1024][1024]
  float*          bqkv = (float*)(ws + 24 * MB);           // 12KB
  unsigned short* QKVc = (unsigned short*)(ws + 25 * MB);  // 32MB [8192][2048] (Q|K)
  unsigned short* Vt   = (unsigned short*)(ws + 57 * MB);  // 16MB [4][1024][2048]
  unsigned short* Sc   = (unsigned short*)(ws + 73 * MB);  // 32MB
  unsigned short* AO   = (unsigned short*)(ws + 0);        // 16MB (over xb)

  const float scale = 0.03125f;  // 1/sqrt(1024)

  cvt_f32_to_bf16<<<(BS * D / 4 + 255) / 256, 256, 0, stream>>>(x, xb, BS * D / 4);
  transpose_w4<<<dim3(32, 32, 4), dim3(32, 32), 0, stream>>>(Wq, Wk, Wv, Wo, Wall);
  concat_bias3<<<12, 256, 0, stream>>>(bq, bk, bv, bqkv);

  // fused QKV projection: N=3072; Q|K -> QKVc[8192][2048], V -> Vt transposed
  gemm_hi<unsigned short, true, true><<<dim3(24, 64, 1), 256, 0, stream>>>(
      xb, Wall, QKVc, bqkv, Vt, D, D, D, 2048, 1.f, 0, 0, 0);

  // scores[b] = scale * Q[b] @ K[b]^T   [2048 x 2048]
  gemm_hi<unsigned short, false, false><<<dim3(16, 16, 4), 256, 0, stream>>>(
      QKVc + 0, QKVc + 1024, Sc, nullptr, nullptr, D, 2048, 2048, S, scale,
      (long)S * 2048, (long)S * 2048, (long)S * S);

  softmax_inplace<<<B * S, 256, 0, stream>>>(Sc, S);

  // attn_out[b] = P[b] @ V[b] via Vt: M=2048, N=1024, K=2048
  gemm_hi<unsigned short, false, false><<<dim3(8, 16, 4), 256, 0, stream>>>(
      Sc, Vt, AO, nullptr, nullptr, S, S, S, D, 1.f,
      (long)S * S, (long)D * S, (long)S * D);

  // out = AO @ Wot^T + bo (fp32), M=8192, N=1024
  gemm_hi<float, true, false><<<dim3(8, 64, 1), 256, 0, stream>>>(
      AO, Wall + 3 * 1024 * 1024, out, bo, nullptr, D, D, D, D, 1.f, 0, 0, 0);
}